// Round 1
// baseline (224.358 us; speedup 1.0000x reference)
//
#include <hip/hip_runtime.h>
#include <hip/hip_bf16.h>
#include <math.h>

#define NB 16
#define SEQ 1024
#define NHEAD 8
#define CHD 64
#define NBH (NB*NHEAD)

typedef __attribute__((ext_vector_type(8))) short short8v;
typedef __attribute__((ext_vector_type(4))) float f32x4;

// workspace layout (bytes)
#define OFF_XN  0u                         // 16*1024 f32  = 65536
#define OFF_HC  65536u                     // 8*4 f32 (padded)
#define OFF_QT  131072u                    // 128*1024*64 bf16 = 16 MiB
#define OFF_KT  (OFF_QT + 16777216u)       // 16 MiB
#define OFF_VP  (OFF_KT + 16777216u)       // 128*1024 f32 = 512 KiB
// total ~34.2 MB

__device__ __forceinline__ short f2bf_raw(float f) {
  union { float f; unsigned u; } un; un.f = f;
  unsigned r = un.u + 0x7fffu + ((un.u >> 16) & 1u);   // RNE
  return (short)(r >> 16);
}

__global__ void k_xn_out(const float* __restrict__ x, const float* __restrict__ g,
                         const float* __restrict__ be, const float* __restrict__ mu,
                         const float* __restrict__ va, const float* __restrict__ bo,
                         float* __restrict__ xn, float* __restrict__ out) {
  int i = blockIdx.x * 256 + threadIdx.x;
  if (i >= NB * SEQ) return;
  int t = i & (SEQ - 1);
  float v = (x[i] - mu[t]) * rsqrtf(va[t] + 1e-5f) * g[t] + be[t];
  xn[i] = v;
  out[i] = v + bo[0];
}

__global__ void k_hcoef(const float* __restrict__ w_in, const float* __restrict__ b_in,
                        const float* __restrict__ w_out, float* __restrict__ hc) {
  int tid = threadIdx.x;
  if (tid >= 32) return;
  int h = tid >> 2, j = tid & 3;
  float s = 0.f;
  for (int c = 0; c < CHD; ++c) {
    int f = h * 64 + c;
    int o = h * 192 + 128 + c;     // v channels
    s += w_out[f] * (j < 3 ? w_in[o * 3 + j] : b_in[o]);
  }
  hc[h * 4 + j] = s;
}

__global__ void k_qkv(const float* __restrict__ w_in, const float* __restrict__ b_in,
                      const float* __restrict__ xn, const float* __restrict__ hc,
                      short* __restrict__ qT, short* __restrict__ kT,
                      float* __restrict__ vp) {
  // grid: b*32 + h*4 + chunk ; 256 threads, one t each
  int bidx = blockIdx.x;
  int chunk = bidx & 3, h = (bidx >> 2) & 7, b = bidx >> 5;
  int t = chunk * 256 + threadIdx.x;
  int bh = b * NHEAD + h;
  float x0 = xn[b * SEQ + t];
  float xm = (t > 0)       ? xn[b * SEQ + t - 1] : 0.f;
  float xp = (t < SEQ - 1) ? xn[b * SEQ + t + 1] : 0.f;
  const float QS = 0.125f * 1.4426950408889634f;  // scale^2 * log2(e)
  long base = ((long)bh * SEQ + t) * CHD;
  for (int c0 = 0; c0 < CHD; c0 += 8) {
    short8v pq, pk;
    #pragma unroll
    for (int u = 0; u < 8; ++u) {
      int oq = h * 192 + c0 + u;            // q channel
      int ok = oq + 64;                      // k channel
      float qv = w_in[oq*3]*xm + w_in[oq*3+1]*x0 + w_in[oq*3+2]*xp + b_in[oq];
      float kv = w_in[ok*3]*xm + w_in[ok*3+1]*x0 + w_in[ok*3+2]*xp + b_in[ok];
      pq[u] = f2bf_raw(qv * QS);
      pk[u] = f2bf_raw(kv);
    }
    *(short8v*)(qT + base + c0) = pq;
    *(short8v*)(kT + base + c0) = pk;
  }
  vp[bh * SEQ + t] = hc[h*4]*xm + hc[h*4+1]*x0 + hc[h*4+2]*xp + hc[h*4+3];
}

__global__ void __launch_bounds__(256) k_attn(const short* __restrict__ qT,
                                              const short* __restrict__ kT,
                                              const float* __restrict__ vp,
                                              float* __restrict__ out) {
  int bid = blockIdx.x;
  int bh = bid >> 4;          // 0..127
  int ttile = bid & 15;       // 0..15
  int tid = threadIdx.x;
  int wave = tid >> 6, lane = tid & 63;
  int l15 = lane & 15, g = lane >> 4;
  int t0 = ttile * 64 + wave * 16;

  const short* qbase = qT + (long)bh * SEQ * CHD;
  const short* kbase = kT + (long)bh * SEQ * CHD;
  const float* vpb = vp + bh * SEQ;

  // A fragments: row = t0 + l15, k = kk*32 + g*8 + j
  short8v a0 = *(const short8v*)(qbase + (t0 + l15) * CHD + g * 8);
  short8v a1 = *(const short8v*)(qbase + (t0 + l15) * CHD + 32 + g * 8);

  float m0=-INFINITY, m1=-INFINITY, m2=-INFINITY, m3=-INFINITY;
  float s0=0, s1=0, s2=0, s3=0, d0=0, d1=0, d2=0, d3=0;

  for (int st = 0; st < SEQ; st += 16) {
    int s = st + l15;
    short8v b0 = *(const short8v*)(kbase + s * CHD + g * 8);
    short8v b1 = *(const short8v*)(kbase + s * CHD + 32 + g * 8);
    float vpv = vpb[s];
    f32x4 acc = {0.f, 0.f, 0.f, 0.f};
    acc = __builtin_amdgcn_mfma_f32_16x16x32_bf16(a0, b0, acc, 0, 0, 0);
    acc = __builtin_amdgcn_mfma_f32_16x16x32_bf16(a1, b1, acc, 0, 0, 0);
    // online update (log2 domain), rows r = 0..3 (row = t0 + g*4 + r)
    #define UPD(r, mm, ss, dd) { float e = acc[r]; float mn = fmaxf(mm, e); \
      float p = exp2f(e - mn); float sc = exp2f(mm - mn); \
      ss = ss * sc + p; dd = dd * sc + p * vpv; mm = mn; }
    UPD(0, m0, s0, d0) UPD(1, m1, s1, d1) UPD(2, m2, s2, d2) UPD(3, m3, s3, d3)
    #undef UPD
  }

  // combine across the 16 lanes of each row group (LSE combine)
  #define RED(mm, ss, dd) \
    for (int mk = 1; mk < 16; mk <<= 1) { \
      float mo = __shfl_xor(mm, mk); float so = __shfl_xor(ss, mk); \
      float dq = __shfl_xor(dd, mk); \
      float mn = fmaxf(mm, mo); \
      float sa = exp2f(mm - mn), sb = exp2f(mo - mn); \
      ss = ss * sa + so * sb; dd = dd * sa + dq * sb; mm = mn; }
  RED(m0, s0, d0) RED(m1, s1, d1) RED(m2, s2, d2) RED(m3, s3, d3)
  #undef RED

  if (l15 == 0) {
    int b = bh >> 3;
    int trow = t0 + g * 4;
    atomicAdd(&out[b * SEQ + trow + 0], d0 / s0);
    atomicAdd(&out[b * SEQ + trow + 1], d1 / s1);
    atomicAdd(&out[b * SEQ + trow + 2], d2 / s2);
    atomicAdd(&out[b * SEQ + trow + 3], d3 / s3);
  }
}

extern "C" void kernel_launch(void* const* d_in, const int* in_sizes, int n_in,
                              void* d_out, int out_size, void* d_ws, size_t ws_size,
                              hipStream_t stream) {
  const float* x   = (const float*)d_in[0];
  const float* g   = (const float*)d_in[1];
  const float* be  = (const float*)d_in[2];
  const float* mu  = (const float*)d_in[3];
  const float* va  = (const float*)d_in[4];
  const float* win = (const float*)d_in[5];
  const float* bin = (const float*)d_in[6];
  const float* wo  = (const float*)d_in[7];
  const float* bo  = (const float*)d_in[8];
  float* out = (float*)d_out;

  char* ws = (char*)d_ws;
  float* xn = (float*)(ws + OFF_XN);
  float* hc = (float*)(ws + OFF_HC);
  short* qT = (short*)(ws + OFF_QT);
  short* kT = (short*)(ws + OFF_KT);
  float* vpj = (float*)(ws + OFF_VP);

  hipLaunchKernelGGL(k_xn_out, dim3(64), dim3(256), 0, stream, x, g, be, mu, va, bo, xn, out);
  hipLaunchKernelGGL(k_hcoef, dim3(1), dim3(64), 0, stream, win, bin, wo, hc);
  hipLaunchKernelGGL(k_qkv, dim3(512), dim3(256), 0, stream, win, bin, xn, hc, qT, kT, vpj);
  hipLaunchKernelGGL(k_attn, dim3(NBH * 16), dim3(256), 0, stream, qT, kT, vpj, out);
}

// Round 2
// 138.301 us; speedup vs baseline: 1.6222x; 1.6222x over previous
//
#include <hip/hip_runtime.h>
#include <hip/hip_bf16.h>
#include <math.h>

#define NB 16
#define SEQ 1024
#define NHEAD 8
#define CHD 64
#define NBH (NB*NHEAD)

typedef __attribute__((ext_vector_type(8))) short short8v;
typedef __attribute__((ext_vector_type(4))) float f32x4;

// workspace layout (bytes)
#define OFF_QT  0u                         // 128*1024*64 bf16 = 16 MiB
#define OFF_KT  (OFF_QT + 16777216u)       // 16 MiB
#define OFF_VP  (OFF_KT + 16777216u)       // 128*1024 f32 = 512 KiB

__device__ __forceinline__ short f2bf_raw(float f) {
  union { float f; unsigned u; } un; un.f = f;
  unsigned r = un.u + 0x7fffu + ((un.u >> 16) & 1u);   // RNE
  return (short)(r >> 16);
}

__device__ __forceinline__ void load_lds16(const void* g, void* l) {
  __builtin_amdgcn_global_load_lds(
      (const __attribute__((address_space(1))) void*)g,
      (__attribute__((address_space(3))) void*)l, 16, 0, 0);
}

// ---------------- prep: BN + conv QKV (bf16) + vproj + out init -------------
__global__ void __launch_bounds__(256) k_prep(
    const float* __restrict__ x, const float* __restrict__ gam,
    const float* __restrict__ be, const float* __restrict__ mu,
    const float* __restrict__ va, const float* __restrict__ w_in,
    const float* __restrict__ b_in, const float* __restrict__ w_out,
    const float* __restrict__ b_out,
    short* __restrict__ qT, short* __restrict__ kT,
    float* __restrict__ vp, float* __restrict__ out) {
  __shared__ float wpack[192][4];   // {w0,w1,w2,b} per channel of this head
  __shared__ float hcs[4];
  int bid = blockIdx.x;
  int tc = bid & 3, h = (bid >> 2) & 7, b = bid >> 5;
  int tid = threadIdx.x;
  if (tid < 192) {
    int o = h * 192 + tid;
    wpack[tid][0] = w_in[o*3]; wpack[tid][1] = w_in[o*3+1];
    wpack[tid][2] = w_in[o*3+2]; wpack[tid][3] = b_in[o];
  }
  __syncthreads();
  if (tid < 4) {
    float s = 0.f;
    for (int c = 0; c < CHD; ++c) s += w_out[h*CHD + c] * wpack[128 + c][tid];
    hcs[tid] = s;
  }
  __syncthreads();

  int t = tc * 256 + tid;
  float x0, xm = 0.f, xp = 0.f;
  {
    float xv = x[b*SEQ + t];
    x0 = (xv - mu[t]) * rsqrtf(va[t] + 1e-5f) * gam[t] + be[t];
    if (t > 0) {
      float q = x[b*SEQ + t - 1];
      xm = (q - mu[t-1]) * rsqrtf(va[t-1] + 1e-5f) * gam[t-1] + be[t-1];
    }
    if (t < SEQ - 1) {
      float q = x[b*SEQ + t + 1];
      xp = (q - mu[t+1]) * rsqrtf(va[t+1] + 1e-5f) * gam[t+1] + be[t+1];
    }
  }
  if (h == 0) out[b*SEQ + t] = x0 + b_out[0];
  int bh = b * NHEAD + h;
  vp[bh*SEQ + t] = hcs[0]*xm + hcs[1]*x0 + hcs[2]*xp + hcs[3];

  const float QS = 0.125f * 1.4426950408889634f;  // scale^2 * log2(e)
  long base = ((long)bh * SEQ + t) * CHD;
  #pragma unroll
  for (int c0 = 0; c0 < CHD; c0 += 8) {
    short8v pq, pk;
    #pragma unroll
    for (int u = 0; u < 8; ++u) {
      float4 wq = *(const float4*)wpack[c0 + u];
      float4 wk = *(const float4*)wpack[64 + c0 + u];
      float qv = wq.x*xm + wq.y*x0 + wq.z*xp + wq.w;
      float kv = wk.x*xm + wk.y*x0 + wk.z*xp + wk.w;
      pq[u] = f2bf_raw(qv * QS);
      pk[u] = f2bf_raw(kv);
    }
    *(short8v*)(qT + base + c0) = pq;
    *(short8v*)(kT + base + c0) = pk;
  }
}

// ---------------- attention: 128 rows/block, K+vp staged in LDS -------------
#define UPD2(mm, ssv, ddv, e0, e1, vv0, vv1) { \
  float mn = fmaxf(fmaxf((e0), (e1)), (mm)); \
  float sc = __builtin_amdgcn_exp2f((mm) - mn); \
  float p0 = __builtin_amdgcn_exp2f((e0) - mn); \
  float p1 = __builtin_amdgcn_exp2f((e1) - mn); \
  ssv = ssv * sc + (p0 + p1); \
  ddv = ddv * sc + (p0*(vv0) + p1*(vv1)); \
  mm = mn; }

__global__ void __launch_bounds__(256) k_attn(const short* __restrict__ qT,
                                              const short* __restrict__ kT,
                                              const float* __restrict__ vp,
                                              float* __restrict__ out) {
  __shared__ char kbuf[8192];     // 2 x 32 cols x 128B, XOR-swizzled content
  __shared__ float vbuf[SEQ];
  int bid = blockIdx.x;
  int bh = bid >> 3;              // 0..127
  int ttile = bid & 7;            // 0..7 (128 rows each)
  int tid = threadIdx.x;
  int wv = tid >> 6, lane = tid & 63;
  int l15 = lane & 15, g = lane >> 4;

  const short* qbase = qT + (long)bh * SEQ * CHD;
  const short* kbase = kT + (long)bh * SEQ * CHD;

  // staging source offset within a 4KB chunk (pre-swizzled so LDS holds
  // granule (r, j') = global granule (r, j'^(r&7)); dest is linear)
  int gidx = wv * 64 + lane;
  int sr = gidx >> 3, sj = gidx & 7;
  int ksrcoff = sr * 128 + ((sj ^ (sr & 7)) * 16);

  // stage vp for this bh (4 KB, linear)
  load_lds16((const char*)(vp + bh*SEQ) + gidx*16, (char*)vbuf + wv*1024);

  // Q fragments: rows trow0 + rg*16 + l15, k = g*8+j (+32 for aB)
  int trow0 = ttile * 128 + wv * 32;
  short8v aA0 = *(const short8v*)(qbase + (trow0 +      l15)*CHD + g*8);
  short8v aB0 = *(const short8v*)(qbase + (trow0 +      l15)*CHD + 32 + g*8);
  short8v aA1 = *(const short8v*)(qbase + (trow0 + 16 + l15)*CHD + g*8);
  short8v aB1 = *(const short8v*)(qbase + (trow0 + 16 + l15)*CHD + 32 + g*8);

  // swizzled ds_read addresses (byte offsets into a 4KB chunk)
  int ra = l15*128 + ((g       ^ (l15 & 7)) * 16);
  int rb = l15*128 + (((g ^ 4) ^ (l15 & 7)) * 16);

  float m0[4], s0[4], d0[4], m1[4], s1[4], d1[4];
  #pragma unroll
  for (int r = 0; r < 4; ++r) {
    m0[r] = -INFINITY; m1[r] = -INFINITY;
    s0[r] = 0.f; s1[r] = 0.f; d0[r] = 0.f; d1[r] = 0.f;
  }

#define STAGEK(CIDX, BOFF) \
  load_lds16((const char*)kbase + (CIDX)*4096 + ksrcoff, kbuf + (BOFF) + wv*1024);

#define COMPUTE(BOFF, CB) { \
  f32x4 acc00, acc01, acc10, acc11; \
  { short8v b0 = *(const short8v*)(kbuf + (BOFF) + ra); \
    short8v b1 = *(const short8v*)(kbuf + (BOFF) + rb); \
    acc00 = __builtin_amdgcn_mfma_f32_16x16x32_bf16(aA0, b0, (f32x4){0,0,0,0}, 0,0,0); \
    acc00 = __builtin_amdgcn_mfma_f32_16x16x32_bf16(aB0, b1, acc00, 0,0,0); \
    acc01 = __builtin_amdgcn_mfma_f32_16x16x32_bf16(aA1, b0, (f32x4){0,0,0,0}, 0,0,0); \
    acc01 = __builtin_amdgcn_mfma_f32_16x16x32_bf16(aB1, b1, acc01, 0,0,0); } \
  { short8v b0 = *(const short8v*)(kbuf + (BOFF) + 2048 + ra); \
    short8v b1 = *(const short8v*)(kbuf + (BOFF) + 2048 + rb); \
    acc10 = __builtin_amdgcn_mfma_f32_16x16x32_bf16(aA0, b0, (f32x4){0,0,0,0}, 0,0,0); \
    acc10 = __builtin_amdgcn_mfma_f32_16x16x32_bf16(aB0, b1, acc10, 0,0,0); \
    acc11 = __builtin_amdgcn_mfma_f32_16x16x32_bf16(aA1, b0, (f32x4){0,0,0,0}, 0,0,0); \
    acc11 = __builtin_amdgcn_mfma_f32_16x16x32_bf16(aB1, b1, acc11, 0,0,0); } \
  float vv0 = vbuf[(CB) + l15], vv1 = vbuf[(CB) + 16 + l15]; \
  _Pragma("unroll") \
  for (int r = 0; r < 4; ++r) { \
    UPD2(m0[r], s0[r], d0[r], acc00[r], acc10[r], vv0, vv1); \
    UPD2(m1[r], s1[r], d1[r], acc01[r], acc11[r], vv0, vv1); \
  } }

  STAGEK(0, 0);
  __syncthreads();
  #pragma unroll 1
  for (int c = 0; c < 32; c += 2) {
    STAGEK(c + 1, 4096);
    COMPUTE(0, c * 32);
    __syncthreads();
    if (c + 2 < 32) STAGEK(c + 2, 0);
    COMPUTE(4096, (c + 1) * 32);
    __syncthreads();
  }

  // 16-lane LSE combine per row
  #define RED(mm, ss, dd) \
    for (int mk = 1; mk < 16; mk <<= 1) { \
      float mo = __shfl_xor(mm, mk); float so = __shfl_xor(ss, mk); \
      float dq = __shfl_xor(dd, mk); \
      float mn = fmaxf(mm, mo); \
      float sa = __builtin_amdgcn_exp2f(mm - mn); \
      float sb = __builtin_amdgcn_exp2f(mo - mn); \
      ss = ss * sa + so * sb; dd = dd * sa + dq * sb; mm = mn; }
  #pragma unroll
  for (int r = 0; r < 4; ++r) {
    RED(m0[r], s0[r], d0[r])
    RED(m1[r], s1[r], d1[r])
  }
  #undef RED

  if (l15 == 0) {
    int b = bh >> 3;
    #pragma unroll
    for (int r = 0; r < 4; ++r) {
      atomicAdd(&out[b*SEQ + trow0 +      g*4 + r], d0[r] / s0[r]);
      atomicAdd(&out[b*SEQ + trow0 + 16 + g*4 + r], d1[r] / s1[r]);
    }
  }
}

extern "C" void kernel_launch(void* const* d_in, const int* in_sizes, int n_in,
                              void* d_out, int out_size, void* d_ws, size_t ws_size,
                              hipStream_t stream) {
  const float* x   = (const float*)d_in[0];
  const float* g   = (const float*)d_in[1];
  const float* be  = (const float*)d_in[2];
  const float* mu  = (const float*)d_in[3];
  const float* va  = (const float*)d_in[4];
  const float* win = (const float*)d_in[5];
  const float* bin = (const float*)d_in[6];
  const float* wo  = (const float*)d_in[7];
  const float* bo  = (const float*)d_in[8];
  float* out = (float*)d_out;

  char* ws = (char*)d_ws;
  short* qT = (short*)(ws + OFF_QT);
  short* kT = (short*)(ws + OFF_KT);
  float* vpj = (float*)(ws + OFF_VP);

  hipLaunchKernelGGL(k_prep, dim3(512), dim3(256), 0, stream,
                     x, g, be, mu, va, win, bin, wo, bo, qT, kT, vpj, out);
  hipLaunchKernelGGL(k_attn, dim3(NBH * 8), dim3(256), 0, stream, qT, kT, vpj, out);
}

// Round 3
// 119.733 us; speedup vs baseline: 1.8738x; 1.1551x over previous
//
#include <hip/hip_runtime.h>
#include <hip/hip_bf16.h>
#include <math.h>

#define NB 16
#define SEQ 1024
#define NHEAD 8
#define CHD 64
#define NBH (NB*NHEAD)

typedef __attribute__((ext_vector_type(8))) short short8v;
typedef __attribute__((ext_vector_type(4))) float f32x4;

// workspace layout (bytes)
#define OFF_QT  0u                         // 128*1024*64 bf16 = 16 MiB
#define OFF_KT  (OFF_QT + 16777216u)       // 16 MiB
#define OFF_VP  (OFF_KT + 16777216u)       // 128*1024 f32 = 512 KiB

__device__ __forceinline__ short f2bf_raw(float f) {
  union { float f; unsigned u; } un; un.f = f;
  unsigned r = un.u + 0x7fffu + ((un.u >> 16) & 1u);   // RNE
  return (short)(r >> 16);
}

__device__ __forceinline__ void load_lds16(const void* g, void* l) {
  __builtin_amdgcn_global_load_lds(
      (const __attribute__((address_space(1))) void*)g,
      (__attribute__((address_space(3))) void*)l, 16, 0, 0);
}

// ---------------- prep: BN + conv QKV (bf16) + vproj + out init -------------
// block = (b, h, tc): 256 t-positions. Thread layout phase2: (tgrp, c_oct):
// each thread computes 8 consecutive t for an 8-channel slice -> every global
// store instruction covers 8 FULL 128B lines (coalesced), not 64 partial.
__global__ void __launch_bounds__(256) k_prep(
    const float* __restrict__ x, const float* __restrict__ gam,
    const float* __restrict__ be, const float* __restrict__ mu,
    const float* __restrict__ va, const float* __restrict__ w_in,
    const float* __restrict__ b_in, const float* __restrict__ w_out,
    const float* __restrict__ b_out,
    short* __restrict__ qT, short* __restrict__ kT,
    float* __restrict__ vp, float* __restrict__ out) {
  __shared__ float xns[264];        // xn[tc*256-1 .. tc*256+256] at index+1
  __shared__ float wpack[192][4];   // {w0,w1,w2,b} per channel of this head
  __shared__ float hcs[4];
  int bid = blockIdx.x;
  int tc = bid & 3, h = (bid >> 2) & 7, b = bid >> 5;
  int tid = threadIdx.x;
  if (tid < 192) {
    int o = h * 192 + tid;
    wpack[tid][0] = w_in[o*3]; wpack[tid][1] = w_in[o*3+1];
    wpack[tid][2] = w_in[o*3+2]; wpack[tid][3] = b_in[o];
  }
  int t0 = tc * 256;
  {
    int tg = t0 + tid;
    float xv = (x[b*SEQ+tg] - mu[tg]) * rsqrtf(va[tg]+1e-5f) * gam[tg] + be[tg];
    xns[tid + 1] = xv;
    if (h == 0) out[b*SEQ + tg] = xv + b_out[0];
    if (tid == 0) {
      int tm = t0 - 1;
      xns[0] = (tm >= 0) ?
        (x[b*SEQ+tm] - mu[tm]) * rsqrtf(va[tm]+1e-5f) * gam[tm] + be[tm] : 0.f;
    }
    if (tid == 255) {
      int tp = t0 + 256;
      xns[257] = (tp < SEQ) ?
        (x[b*SEQ+tp] - mu[tp]) * rsqrtf(va[tp]+1e-5f) * gam[tp] + be[tp] : 0.f;
    }
  }
  __syncthreads();
  if (tid < 4) {
    float s = 0.f;
    for (int c = 0; c < CHD; ++c) s += w_out[h*CHD + c] * wpack[128 + c][tid];
    hcs[tid] = s;
  }
  __syncthreads();

  int bh = b * NHEAD + h;
  vp[bh*SEQ + t0 + tid] =
      hcs[0]*xns[tid] + hcs[1]*xns[tid+1] + hcs[2]*xns[tid+2] + hcs[3];

  const float QS = 0.125f * 1.4426950408889634f;  // scale^2 * log2(e)
  int c_oct = tid & 7, tgrp = tid >> 3;           // 8 ch x 8 t per thread
  long tbase = ((long)bh * SEQ + t0 + tgrp*8);
  #pragma unroll
  for (int i = 0; i < 8; ++i) {
    int tl = tgrp*8 + i;
    float xm = xns[tl], x0 = xns[tl+1], xp = xns[tl+2];
    short8v pq, pk;
    #pragma unroll
    for (int u = 0; u < 8; ++u) {
      int c = c_oct*8 + u;
      float4 wq = *(const float4*)wpack[c];
      float4 wk = *(const float4*)wpack[64 + c];
      pq[u] = f2bf_raw((wq.x*xm + wq.y*x0 + wq.z*xp + wq.w) * QS);
      pk[u] = f2bf_raw(wk.x*xm + wk.y*x0 + wk.z*xp + wk.w);
    }
    *(short8v*)(qT + (tbase + i)*CHD + c_oct*8) = pq;
    *(short8v*)(kT + (tbase + i)*CHD + c_oct*8) = pk;
  }
}

// ---------------- attention: 128 rows/block, K+vp staged in LDS -------------
// no online max: scores (log2 domain) are ~|e|<15, exp2 overflow needs >126.
#define UPD2(ssv, ddv, e0, e1, vv0, vv1) { \
  float p0 = __builtin_amdgcn_exp2f(e0); \
  float p1 = __builtin_amdgcn_exp2f(e1); \
  ssv += p0 + p1; \
  ddv = fmaf(p0, (vv0), fmaf(p1, (vv1), ddv)); }

__global__ void __launch_bounds__(256) k_attn(const short* __restrict__ qT,
                                              const short* __restrict__ kT,
                                              const float* __restrict__ vp,
                                              float* __restrict__ out) {
  __shared__ char kbuf[8192];     // 2 x 32 cols x 128B, XOR-swizzled content
  __shared__ float vbuf[SEQ];
  int bid = blockIdx.x;
  // XCD-friendly: all 8 ttiles of a bh have bid%8 == bh%8 -> same XCD L2
  int bh = bid & 127;             // 0..127
  int ttile = bid >> 7;           // 0..7 (128 rows each)
  int tid = threadIdx.x;
  int wv = tid >> 6, lane = tid & 63;
  int l15 = lane & 15, g = lane >> 4;

  const short* qbase = qT + (long)bh * SEQ * CHD;
  const short* kbase = kT + (long)bh * SEQ * CHD;

  // staging source offset within a 4KB chunk (pre-swizzled so LDS holds
  // granule (r, j') = global granule (r, j'^(r&7)); dest is linear)
  int gidx = wv * 64 + lane;
  int sr = gidx >> 3, sj = gidx & 7;
  int ksrcoff = sr * 128 + ((sj ^ (sr & 7)) * 16);

  // stage vp for this bh (4 KB, linear)
  load_lds16((const char*)(vp + bh*SEQ) + gidx*16, (char*)vbuf + wv*1024);

  // Q fragments: rows trow0 + rg*16 + l15, k = g*8+j (+32 for aB)
  int trow0 = ttile * 128 + wv * 32;
  short8v aA0 = *(const short8v*)(qbase + (trow0 +      l15)*CHD + g*8);
  short8v aB0 = *(const short8v*)(qbase + (trow0 +      l15)*CHD + 32 + g*8);
  short8v aA1 = *(const short8v*)(qbase + (trow0 + 16 + l15)*CHD + g*8);
  short8v aB1 = *(const short8v*)(qbase + (trow0 + 16 + l15)*CHD + 32 + g*8);

  // swizzled ds_read addresses (byte offsets into a 4KB chunk)
  int ra = l15*128 + ((g       ^ (l15 & 7)) * 16);
  int rb = l15*128 + (((g ^ 4) ^ (l15 & 7)) * 16);

  float s0[4], d0[4], s1[4], d1[4];
  #pragma unroll
  for (int r = 0; r < 4; ++r) { s0[r]=0.f; s1[r]=0.f; d0[r]=0.f; d1[r]=0.f; }

#define STAGEK(CIDX, BOFF) \
  load_lds16((const char*)kbase + (CIDX)*4096 + ksrcoff, kbuf + (BOFF) + wv*1024);

#define COMPUTE(BOFF, CB) { \
  f32x4 acc00, acc01, acc10, acc11; \
  { short8v b0 = *(const short8v*)(kbuf + (BOFF) + ra); \
    short8v b1 = *(const short8v*)(kbuf + (BOFF) + rb); \
    acc00 = __builtin_amdgcn_mfma_f32_16x16x32_bf16(aA0, b0, (f32x4){0,0,0,0}, 0,0,0); \
    acc00 = __builtin_amdgcn_mfma_f32_16x16x32_bf16(aB0, b1, acc00, 0,0,0); \
    acc01 = __builtin_amdgcn_mfma_f32_16x16x32_bf16(aA1, b0, (f32x4){0,0,0,0}, 0,0,0); \
    acc01 = __builtin_amdgcn_mfma_f32_16x16x32_bf16(aB1, b1, acc01, 0,0,0); } \
  { short8v b0 = *(const short8v*)(kbuf + (BOFF) + 2048 + ra); \
    short8v b1 = *(const short8v*)(kbuf + (BOFF) + 2048 + rb); \
    acc10 = __builtin_amdgcn_mfma_f32_16x16x32_bf16(aA0, b0, (f32x4){0,0,0,0}, 0,0,0); \
    acc10 = __builtin_amdgcn_mfma_f32_16x16x32_bf16(aB0, b1, acc10, 0,0,0); \
    acc11 = __builtin_amdgcn_mfma_f32_16x16x32_bf16(aA1, b0, (f32x4){0,0,0,0}, 0,0,0); \
    acc11 = __builtin_amdgcn_mfma_f32_16x16x32_bf16(aB1, b1, acc11, 0,0,0); } \
  float vv0 = vbuf[(CB) + l15], vv1 = vbuf[(CB) + 16 + l15]; \
  _Pragma("unroll") \
  for (int r = 0; r < 4; ++r) { \
    UPD2(s0[r], d0[r], acc00[r], acc10[r], vv0, vv1); \
    UPD2(s1[r], d1[r], acc01[r], acc11[r], vv0, vv1); \
  } }

  STAGEK(0, 0);
  __syncthreads();
  #pragma unroll 1
  for (int c = 0; c < 32; c += 2) {
    STAGEK(c + 1, 4096);
    COMPUTE(0, c * 32);
    __syncthreads();
    if (c + 2 < 32) STAGEK(c + 2, 0);
    COMPUTE(4096, (c + 1) * 32);
    __syncthreads();
  }

  // sum across the 16 lanes of each row group
  #pragma unroll
  for (int r = 0; r < 4; ++r) {
    #pragma unroll
    for (int mk = 1; mk < 16; mk <<= 1) {
      s0[r] += __shfl_xor(s0[r], mk); d0[r] += __shfl_xor(d0[r], mk);
      s1[r] += __shfl_xor(s1[r], mk); d1[r] += __shfl_xor(d1[r], mk);
    }
  }

  if (l15 == 0) {
    int b = bh >> 3;
    #pragma unroll
    for (int r = 0; r < 4; ++r) {
      atomicAdd(&out[b*SEQ + trow0 +      g*4 + r], d0[r] / s0[r]);
      atomicAdd(&out[b*SEQ + trow0 + 16 + g*4 + r], d1[r] / s1[r]);
    }
  }
}

extern "C" void kernel_launch(void* const* d_in, const int* in_sizes, int n_in,
                              void* d_out, int out_size, void* d_ws, size_t ws_size,
                              hipStream_t stream) {
  const float* x   = (const float*)d_in[0];
  const float* g   = (const float*)d_in[1];
  const float* be  = (const float*)d_in[2];
  const float* mu  = (const float*)d_in[3];
  const float* va  = (const float*)d_in[4];
  const float* win = (const float*)d_in[5];
  const float* bin = (const float*)d_in[6];
  const float* wo  = (const float*)d_in[7];
  const float* bo  = (const float*)d_in[8];
  float* out = (float*)d_out;

  char* ws = (char*)d_ws;
  short* qT = (short*)(ws + OFF_QT);
  short* kT = (short*)(ws + OFF_KT);
  float* vpj = (float*)(ws + OFF_VP);

  hipLaunchKernelGGL(k_prep, dim3(512), dim3(256), 0, stream,
                     x, g, be, mu, va, win, bin, wo, bo, qT, kT, vpj, out);
  hipLaunchKernelGGL(k_attn, dim3(NBH * 8), dim3(256), 0, stream, qT, kT, vpj, out);
}

// Round 5
// 116.954 us; speedup vs baseline: 1.9183x; 1.0238x over previous
//
#include <hip/hip_runtime.h>
#include <hip/hip_bf16.h>
#include <math.h>

#define NB 16
#define SEQ 1024
#define NHEAD 8
#define CHD 64
#define NBH (NB*NHEAD)

typedef __attribute__((ext_vector_type(8))) short short8v;
typedef __attribute__((ext_vector_type(4))) float f32x4;

// workspace layout (bytes)
#define OFF_QT  0u                         // 128*1024*64 bf16 = 16 MiB
#define OFF_KT  (OFF_QT + 16777216u)       // 16 MiB
#define OFF_VP  (OFF_KT + 16777216u)       // 128*1024 f32 = 512 KiB

__device__ __forceinline__ short f2bf_raw(float f) {
  union { float f; unsigned u; } un; un.f = f;
  unsigned r = un.u + 0x7fffu + ((un.u >> 16) & 1u);   // RNE
  return (short)(r >> 16);
}

__device__ __forceinline__ void load_lds16(const void* g, void* l) {
  __builtin_amdgcn_global_load_lds(
      (const __attribute__((address_space(1))) void*)g,
      (__attribute__((address_space(3))) void*)l, 16, 0, 0);
}

// ---------------- prep: BN + conv QKV (bf16) + vproj + out init -------------
// thread = (tgrp, c_oct): 8 consecutive t x 8-channel slice; stores cover
// full 128B lines. Conv weights register-cached (wpack LDS reads in the hot
// loop were an 8-way bank conflict: 8-row lane-group stride = 128B).
__global__ void __launch_bounds__(256) k_prep(
    const float* __restrict__ x, const float* __restrict__ gam,
    const float* __restrict__ be, const float* __restrict__ mu,
    const float* __restrict__ va, const float* __restrict__ w_in,
    const float* __restrict__ b_in, const float* __restrict__ w_out,
    const float* __restrict__ b_out,
    short* __restrict__ qT, short* __restrict__ kT,
    float* __restrict__ vp, float* __restrict__ out) {
  __shared__ float xns[264];        // xn[t0-1 .. t0+256] at index+1
  __shared__ float wpack[192][4];   // {w0,w1,w2,b} per channel of this head
  __shared__ float hcs[4];
  int bid = blockIdx.x;
  int tc = bid & 3, h = (bid >> 2) & 7, b = bid >> 5;
  int tid = threadIdx.x;
  if (tid < 192) {
    int o = h * 192 + tid;
    wpack[tid][0] = w_in[o*3]; wpack[tid][1] = w_in[o*3+1];
    wpack[tid][2] = w_in[o*3+2]; wpack[tid][3] = b_in[o];
  }
  int t0 = tc * 256;
  {
    int tg = t0 + tid;
    float xv = (x[b*SEQ+tg] - mu[tg]) * rsqrtf(va[tg]+1e-5f) * gam[tg] + be[tg];
    xns[tid + 1] = xv;
    if (h == 0) out[b*SEQ + tg] = xv + b_out[0];
    if (tid == 0) {
      int tm = t0 - 1;
      xns[0] = (tm >= 0) ?
        (x[b*SEQ+tm] - mu[tm]) * rsqrtf(va[tm]+1e-5f) * gam[tm] + be[tm] : 0.f;
    }
    if (tid == 255) {
      int tp = t0 + 256;
      xns[257] = (tp < SEQ) ?
        (x[b*SEQ+tp] - mu[tp]) * rsqrtf(va[tp]+1e-5f) * gam[tp] + be[tp] : 0.f;
    }
  }
  __syncthreads();
  if (tid < 4) {
    float s = 0.f;
    for (int c = 0; c < CHD; ++c) s += w_out[h*CHD + c] * wpack[128 + c][tid];
    hcs[tid] = s;
  }

  // register-cache this thread's 16 weight quads (one-time LDS reads)
  int c_oct = tid & 7, tgrp = tid >> 3;
  float4 rq[8], rk[8];
  #pragma unroll
  for (int u = 0; u < 8; ++u) {
    rq[u] = *(const float4*)wpack[c_oct*8 + u];
    rk[u] = *(const float4*)wpack[64 + c_oct*8 + u];
  }
  __syncthreads();   // hcs ready

  int bh = b * NHEAD + h;
  vp[bh*SEQ + t0 + tid] =
      hcs[0]*xns[tid] + hcs[1]*xns[tid+1] + hcs[2]*xns[tid+2] + hcs[3];

  const float QS = 0.125f * 1.4426950408889634f;  // scale^2 * log2(e)
  long tbase = ((long)bh * SEQ + t0 + tgrp*8);
  #pragma unroll
  for (int i = 0; i < 8; ++i) {
    int tl = tgrp*8 + i;
    float xm = xns[tl], x0 = xns[tl+1], xp = xns[tl+2];
    short8v pq, pk;
    #pragma unroll
    for (int u = 0; u < 8; ++u) {
      pq[u] = f2bf_raw((rq[u].x*xm + rq[u].y*x0 + rq[u].z*xp + rq[u].w) * QS);
      pk[u] = f2bf_raw(rk[u].x*xm + rk[u].y*x0 + rk[u].z*xp + rk[u].w);
    }
    *(short8v*)(qT + (tbase + i)*CHD + c_oct*8) = pq;
    *(short8v*)(kT + (tbase + i)*CHD + c_oct*8) = pk;
  }
}

// ---------------- attention: 128 rows/block, per-wave K staging -------------
// no online max: scores (log2 domain) are ~|e|<15, exp2 overflow needs >126.
// Each wave double-buffers its own 4KB K chunks: NO __syncthreads in the
// main loop, only per-wave counted s_waitcnt vmcnt(N).
#define UPD2(ssv, ddv, e0, e1, vv0, vv1) { \
  float p0 = __builtin_amdgcn_exp2f(e0); \
  float p1 = __builtin_amdgcn_exp2f(e1); \
  ssv += p0 + p1; \
  ddv = fmaf(p0, (vv0), fmaf(p1, (vv1), ddv)); }

__global__ void __launch_bounds__(256) k_attn(const short* __restrict__ qT,
                                              const short* __restrict__ kT,
                                              const float* __restrict__ vp,
                                              float* __restrict__ out) {
  __shared__ char kbuf[4][2][4096];   // [wave][dbuf][32 cols x 128B] swizzled
  __shared__ float vbuf[SEQ];
  int bid = blockIdx.x;
  // XCD-friendly: all 8 ttiles of a bh share bid%8 -> same XCD L2
  int bh = bid & 127;
  int ttile = bid >> 7;
  int tid = threadIdx.x;
  int wv = tid >> 6, lane = tid & 63;
  int l15 = lane & 15, g = lane >> 4;

  const short* qbase = qT + (long)bh * SEQ * CHD;
  const short* kbase = kT + (long)bh * SEQ * CHD;

  // per-lane pre-swizzled source offset: LDS granule (r, j') holds global
  // granule (r, j'^(r&7));  granule index gi = i*64+lane -> r=gi>>3, j'=gi&7
  int base_swz = (lane >> 3) * 128 + (((lane & 7) ^ ((lane >> 3) & 7)) * 16);

  // stage vp for this bh (each wave 1KB, linear)
  load_lds16((const char*)(vp + bh*SEQ) + (wv*64 + lane)*16,
             (char*)vbuf + wv*1024);

#define STAGEW(CIDX, DBUF) { \
  const char* sp_ = (const char*)kbase + (CIDX)*4096 + base_swz; \
  char* dp_ = &kbuf[wv][DBUF][0]; \
  load_lds16(sp_ +    0, dp_ +    0); \
  load_lds16(sp_ + 1024, dp_ + 1024); \
  load_lds16(sp_ + 2048, dp_ + 2048); \
  load_lds16(sp_ + 3072, dp_ + 3072); }

  // Q fragments: rows trow0 + rg*16 + l15, k = g*8+j (+32 for aB)
  int trow0 = ttile * 128 + wv * 32;
  short8v aA0 = *(const short8v*)(qbase + (trow0 +      l15)*CHD + g*8);
  short8v aB0 = *(const short8v*)(qbase + (trow0 +      l15)*CHD + 32 + g*8);
  short8v aA1 = *(const short8v*)(qbase + (trow0 + 16 + l15)*CHD + g*8);
  short8v aB1 = *(const short8v*)(qbase + (trow0 + 16 + l15)*CHD + 32 + g*8);

  STAGEW(0, 0);
  STAGEW(1, 1);

  // swizzled ds_read byte offsets within a 4KB chunk
  int ra = l15*128 + ((g       ^ (l15 & 7)) * 16);
  int rb = l15*128 + (((g ^ 4) ^ (l15 & 7)) * 16);

  float s0[4], d0[4], s1[4], d1[4];
  #pragma unroll
  for (int r = 0; r < 4; ++r) { s0[r]=0.f; s1[r]=0.f; d0[r]=0.f; d1[r]=0.f; }

#define COMPUTE(DBUF, CB) { \
  const char* kb = &kbuf[wv][DBUF][0]; \
  f32x4 acc00, acc01, acc10, acc11; \
  { short8v b0 = *(const short8v*)(kb + ra); \
    short8v b1 = *(const short8v*)(kb + rb); \
    acc00 = __builtin_amdgcn_mfma_f32_16x16x32_bf16(aA0, b0, (f32x4){0,0,0,0}, 0,0,0); \
    acc00 = __builtin_amdgcn_mfma_f32_16x16x32_bf16(aB0, b1, acc00, 0,0,0); \
    acc01 = __builtin_amdgcn_mfma_f32_16x16x32_bf16(aA1, b0, (f32x4){0,0,0,0}, 0,0,0); \
    acc01 = __builtin_amdgcn_mfma_f32_16x16x32_bf16(aB1, b1, acc01, 0,0,0); } \
  { short8v b0 = *(const short8v*)(kb + 2048 + ra); \
    short8v b1 = *(const short8v*)(kb + 2048 + rb); \
    acc10 = __builtin_amdgcn_mfma_f32_16x16x32_bf16(aA0, b0, (f32x4){0,0,0,0}, 0,0,0); \
    acc10 = __builtin_amdgcn_mfma_f32_16x16x32_bf16(aB0, b1, acc10, 0,0,0); \
    acc11 = __builtin_amdgcn_mfma_f32_16x16x32_bf16(aA1, b0, (f32x4){0,0,0,0}, 0,0,0); \
    acc11 = __builtin_amdgcn_mfma_f32_16x16x32_bf16(aB1, b1, acc11, 0,0,0); } \
  float vv0 = vbuf[(CB) + l15], vv1 = vbuf[(CB) + 16 + l15]; \
  _Pragma("unroll") \
  for (int r = 0; r < 4; ++r) { \
    UPD2(s0[r], d0[r], acc00[r], acc10[r], vv0, vv1); \
    UPD2(s1[r], d1[r], acc01[r], acc11[r], vv0, vv1); \
  } }

  __syncthreads();   // vbuf + chunks 0,1 staged (barrier drains vmcnt)

  #pragma unroll 1
  for (int c = 0; c < 31; ++c) {
    // chunk c ready when only the newest 4 loads (chunk c+1) are outstanding
    asm volatile("s_waitcnt vmcnt(4)" ::: "memory");
    COMPUTE(c & 1, c * 32);
    asm volatile("" ::: "memory");   // keep stage below the buffer reads
    if (c + 2 < 32) STAGEW(c + 2, c & 1);
  }
  asm volatile("s_waitcnt vmcnt(0)" ::: "memory");
  COMPUTE(1, 31 * 32);

  // sum across the 16 lanes of each row group
  #pragma unroll
  for (int r = 0; r < 4; ++r) {
    #pragma unroll
    for (int mk = 1; mk < 16; mk <<= 1) {
      s0[r] += __shfl_xor(s0[r], mk); d0[r] += __shfl_xor(d0[r], mk);
      s1[r] += __shfl_xor(s1[r], mk); d1[r] += __shfl_xor(d1[r], mk);
    }
  }

  if (l15 == 0) {
    int b = bh >> 3;
    #pragma unroll
    for (int r = 0; r < 4; ++r) {
      atomicAdd(&out[b*SEQ + trow0 +      g*4 + r], d0[r] / s0[r]);
      atomicAdd(&out[b*SEQ + trow0 + 16 + g*4 + r], d1[r] / s1[r]);
    }
  }
}

extern "C" void kernel_launch(void* const* d_in, const int* in_sizes, int n_in,
                              void* d_out, int out_size, void* d_ws, size_t ws_size,
                              hipStream_t stream) {
  const float* x   = (const float*)d_in[0];
  const float* g   = (const float*)d_in[1];
  const float* be  = (const float*)d_in[2];
  const float* mu  = (const float*)d_in[3];
  const float* va  = (const float*)d_in[4];
  const float* win = (const float*)d_in[5];
  const float* bin = (const float*)d_in[6];
  const float* wo  = (const float*)d_in[7];
  const float* bo  = (const float*)d_in[8];
  float* out = (float*)d_out;

  char* ws = (char*)d_ws;
  short* qT = (short*)(ws + OFF_QT);
  short* kT = (short*)(ws + OFF_KT);
  float* vpj = (float*)(ws + OFF_VP);

  hipLaunchKernelGGL(k_prep, dim3(512), dim3(256), 0, stream,
                     x, g, be, mu, va, win, bin, wo, bo, qT, kT, vpj, out);
  hipLaunchKernelGGL(k_attn, dim3(NBH * 8), dim3(256), 0, stream, qT, kT, vpj, out);
}

// Round 7
// 97.661 us; speedup vs baseline: 2.2973x; 1.1976x over previous
//
#include <hip/hip_runtime.h>
#include <hip/hip_bf16.h>
#include <math.h>

#define NB 16
#define SEQ 1024
#define NHEAD 8
#define NBH (NB*NHEAD)

typedef __attribute__((ext_vector_type(4))) float f32x4;

// ws layout (bytes)
#define OFF_XN 0u                       // 16*1024 f32 = 64 KB
#define OFF_VP 65536u                   // 128*1024 f32 = 512 KB
#define OFF_M  (65536u + 524288u)       // 8*16 f32 = 512 B

__device__ __forceinline__ void load_lds16(const void* g, void* l) {
  __builtin_amdgcn_global_load_lds(
      (const __attribute__((address_space(1))) void*)g,
      (__attribute__((address_space(3))) void*)l, 16, 0, 0);
}

// ---- prep: BN -> xn; out init; vp = (w_out o V)(xn); M = scale^2 Wq'^T Wk' ----
// block = (b,h), 256 threads, each 4 consecutive t.
__global__ void __launch_bounds__(256) k_prep(
    const float* __restrict__ x, const float* __restrict__ gam,
    const float* __restrict__ be, const float* __restrict__ mu,
    const float* __restrict__ va, const float* __restrict__ w_in,
    const float* __restrict__ b_in, const float* __restrict__ w_out,
    const float* __restrict__ b_out,
    float* __restrict__ xng, float* __restrict__ vpg,
    float* __restrict__ Mws, float* __restrict__ out) {
  __shared__ float xsl[1025];     // xsl[0..1023] = xn(b,:), xsl[1024] = 0 guard
  __shared__ float hcs[4];
  int bid = blockIdx.x;
  int b = bid >> 3, h = bid & 7;
  int tid = threadIdx.x;
  int t4 = tid * 4;

  // BatchNorm (vectorized 4 t's per thread)
  f32x4 xv = *(const f32x4*)(x + b*SEQ + t4);
  f32x4 muv = *(const f32x4*)(mu + t4);
  f32x4 vav = *(const f32x4*)(va + t4);
  f32x4 gv  = *(const f32x4*)(gam + t4);
  f32x4 bev = *(const f32x4*)(be + t4);
  f32x4 xn4;
  #pragma unroll
  for (int u = 0; u < 4; ++u)
    xn4[u] = (xv[u] - muv[u]) * rsqrtf(vav[u] + 1e-5f) * gv[u] + bev[u];
  *(f32x4*)(xsl + t4) = xn4;
  if (tid == 0) xsl[1024] = 0.f;
  if (h == 0) {
    *(f32x4*)(xng + b*SEQ + t4) = xn4;
    float bo = b_out[0];
    f32x4 o4 = {xn4[0]+bo, xn4[1]+bo, xn4[2]+bo, xn4[3]+bo};
    *(f32x4*)(out + b*SEQ + t4) = o4;
  }

  // hc[j] = sum_c w_out[h,c] * Wv'[c,j]  (thread = (j, c): one product, wave-reduce)
  {
    int j = tid >> 6, c = tid & 63;          // each wave has uniform j
    int o = h*192 + 128 + c;
    float wv = (j < 3) ? w_in[o*3 + j] : b_in[o];
    float p = w_out[h*64 + c] * wv;
    #pragma unroll
    for (int mk = 1; mk < 64; mk <<= 1) p += __shfl_xor(p, mk);
    if (c == 0) hcs[j] = p;
  }

  // M[i][j] = QS2 * sum_c Wq'[c,i]*Wk'[c,j]  (thread = (ij, c-quad); 16-lane reduce)
  {
    int ij = tid >> 4, cq = tid & 15;
    int i = ij >> 2, j = ij & 3;
    float acc = 0.f;
    #pragma unroll
    for (int u = 0; u < 4; ++u) {
      int c = cq*4 + u;
      int oq = h*192 + c, ok = oq + 64;
      float wq = (i < 3) ? w_in[oq*3 + i] : b_in[oq];
      float wk = (j < 3) ? w_in[ok*3 + j] : b_in[ok];
      acc = fmaf(wq, wk, acc);
    }
    #pragma unroll
    for (int mk = 1; mk < 16; mk <<= 1) acc += __shfl_xor(acc, mk);
    // benign race: all 16 b-blocks write identical values
    if (cq == 0) Mws[h*16 + ij] = acc * (0.125f * 1.4426950408889634f);
  }
  __syncthreads();

  // vp(b,h,t) = hc0*xn[t-1] + hc1*xn[t] + hc2*xn[t+1] + hc3
  float hc0 = hcs[0], hc1 = hcs[1], hc2 = hcs[2], hc3 = hcs[3];
  f32x4 vp4;
  #pragma unroll
  for (int u = 0; u < 4; ++u) {
    int t = t4 + u;
    float xm = (t > 0) ? xsl[t-1] : 0.f;
    float xp = xsl[t+1];                    // t=1023 -> guard 0
    vp4[u] = fmaf(hc0, xm, fmaf(hc1, xsl[t], fmaf(hc2, xp, hc3)));
  }
  *(f32x4*)(vpg + (b*NHEAD + h)*SEQ + t4) = vp4;
}

// ---- attention: score(t,s) = a0*xn[s-1]+a1*xn[s]+a2*xn[s+1]+a3 (per head) ----
// block = (bh, t-chunk of 256); thread owns one t; s-loop over LDS broadcasts.
// No MFMA, no cross-lane reduce, no online max (|score| << 126 in log2 domain).
__global__ void __launch_bounds__(256) k_attn(
    const float* __restrict__ xng, const float* __restrict__ vpg,
    const float* __restrict__ Mws, float* __restrict__ out) {
  __shared__ float xsl[1032];   // xn row + 8 zero pad
  __shared__ float vps[1032];   // vp row + 8 zero pad
  __shared__ float Ms[16];
  int bid = blockIdx.x;
  int bh = bid & 127, chunk = bid >> 7;   // chunks of same bh share an XCD
  int b = bh >> 3, h = bh & 7;
  int tid = threadIdx.x;

  load_lds16((const char*)(xng + b*SEQ)  + tid*16, (char*)xsl + tid*16);
  load_lds16((const char*)(vpg + bh*SEQ) + tid*16, (char*)vps + tid*16);
  if (tid < 8) { xsl[1024+tid] = 0.f; vps[1024+tid] = 0.f; }
  if (tid < 16) Ms[tid] = Mws[h*16 + tid];
  __syncthreads();

  int t = chunk*256 + tid;
  float um = (t > 0) ? xsl[t-1] : 0.f;
  float u0 = xsl[t], up = xsl[t+1];
  float a0 = fmaf(um, Ms[0], fmaf(u0, Ms[4],  fmaf(up, Ms[8],  Ms[12])));
  float a1 = fmaf(um, Ms[1], fmaf(u0, Ms[5],  fmaf(up, Ms[9],  Ms[13])));
  float a2 = fmaf(um, Ms[2], fmaf(u0, Ms[6],  fmaf(up, Ms[10], Ms[14])));
  float a3 = fmaf(um, Ms[3], fmaf(u0, Ms[7],  fmaf(up, Ms[11], Ms[15])));

  const f32x4* x4 = (const f32x4*)xsl;
  const f32x4* v4 = (const f32x4*)vps;
  float ss = 0.f, dd = 0.f;
  f32x4 cA = x4[0], vA = v4[0];
  f32x4 cB = x4[1], vB = v4[1];
  float prevW = 0.f;                       // xn[-1] = 0 (conv zero-pad)

#define STEP(XM, X0, XP, VV) { \
  float sc = fmaf(a0, (XM), fmaf(a1, (X0), fmaf(a2, (XP), a3))); \
  float p = __builtin_amdgcn_exp2f(sc); \
  ss += p; dd = fmaf(p, (VV), dd); }

  #pragma unroll 4
  for (int k = 0; k < 256; ++k) {
    f32x4 cC = x4[k+2];                    // k=254,255 hit zero pads
    f32x4 vC = v4[k+2];
    STEP(prevW, cA.x, cA.y, vA.x)
    STEP(cA.x,  cA.y, cA.z, vA.y)
    STEP(cA.y,  cA.z, cA.w, vA.z)
    STEP(cA.z,  cA.w, cB.x, vA.w)
    prevW = cA.w; cA = cB; cB = cC; vA = vB; vB = vC;
  }
#undef STEP

  atomicAdd(&out[b*SEQ + t], dd / ss);     // 8 heads accumulate per out elem
}

extern "C" void kernel_launch(void* const* d_in, const int* in_sizes, int n_in,
                              void* d_out, int out_size, void* d_ws, size_t ws_size,
                              hipStream_t stream) {
  const float* x   = (const float*)d_in[0];
  const float* g   = (const float*)d_in[1];
  const float* be  = (const float*)d_in[2];
  const float* mu  = (const float*)d_in[3];
  const float* va  = (const float*)d_in[4];
  const float* win = (const float*)d_in[5];
  const float* bin = (const float*)d_in[6];
  const float* wo  = (const float*)d_in[7];
  const float* bo  = (const float*)d_in[8];
  float* out = (float*)d_out;

  char* ws = (char*)d_ws;
  float* xng = (float*)(ws + OFF_XN);
  float* vpg = (float*)(ws + OFF_VP);
  float* Mws = (float*)(ws + OFF_M);

  hipLaunchKernelGGL(k_prep, dim3(NBH), dim3(256), 0, stream,
                     x, g, be, mu, va, win, bin, wo, bo, xng, vpg, Mws, out);
  hipLaunchKernelGGL(k_attn, dim3(NBH * 4), dim3(256), 0, stream,
                     xng, vpg, Mws, out);
}